// Round 7
// baseline (406.722 us; speedup 1.0000x reference)
//
#include <hip/hip_runtime.h>
#include <stdint.h>

#define BB 128
#define TT 3000
#define CC 64
#define LL 128
// S = 2L+1 = 257
#define NEG (-1e30f)
#define LOG2E 1.4426950408889634f
#define LN2f 0.6931471805599453f
#define DPTH 8                // prefetch depth in steps; 3000 = 8*375
#define LSE_BLOCKS 1024       // extra blocks doing the softmax-normalizer pass

__device__ __forceinline__ float fexp2(float x) { return __builtin_amdgcn_exp2f(x); }
__device__ __forceinline__ float flog2(float x) { return __builtin_amdgcn_logf(x); }

// base-2 logsumexp of two base-2 log-domain values (6 VALU)
__device__ __forceinline__ float lse2(float x, float y) {
    float m = fmaxf(x, y);
    float e = fexp2(-fabsf(x - y));          // v_exp_f32 with -|.| src modifier
    return m + flog2(1.0f + e);
}
// lane l gets lane l-1's value (lane 0 gets NEG) via DPP wave_shr:1 — VALU speed
__device__ __forceinline__ float shr1_neg(float x) {
    int r = __builtin_amdgcn_update_dpp(__float_as_int(NEG), __float_as_int(x),
                                        0x138 /*wave_shr:1*/, 0xF, 0xF, false);
    return __int_as_float(r);
}
// per-step wall: loads may not cross (may-write-memory asm), zero instructions
#define MWALL() asm volatile("" ::: "memory")

// Fused kernel.
// Blocks 0..BB-1 : CTC forward scan for batch b. One wave. Emissions stream
//                  through a rolling 8-step register window: consume slot k,
//                  then reload slot k for step t+8 (plain loads, pinned to
//                  their step by MWALL); compiler inserts counted vmcnt(21)
//                  before each consume — 24 loads stay in flight.
// Blocks BB..    : per-(b,t)-row softmax normalizer on otherwise-idle CUs
//                  (also warms L3 for the scan's gathers).
__global__ __launch_bounds__(256) void fused_kernel(const float* __restrict__ in,
                                                    const int* __restrict__ tgt,
                                                    float* __restrict__ lse,
                                                    float* __restrict__ ll2) {
    if (blockIdx.x < BB) {
        if (threadIdx.x >= 64) return;       // scan uses wave 0 only
        __builtin_amdgcn_s_setprio(1);       // protect issue slots from lse waves
        int b = blockIdx.x;
        int lane = threadIdx.x;
        const float* fb = in + (size_t)b * TT * CC;
        int t0 = tgt[b * LL + 2 * lane];     // channel for odd state 4l+1
        int t1 = tgt[b * LL + 2 * lane + 1]; // channel for odd state 4l+3
        const float* p1 = fb + t0;           // stream: odd state 4l+1 (stride CC)
        const float* p3 = fb + t1;           // stream: odd state 4l+3
        const float* pB = fb + 63;           // stream: blank channel

        // rolling window, slot k holds frame t with t % DPTH == k
        float w1[DPTH], w3[DPTH], wB[DPTH];
        #pragma unroll
        for (int k = 0; k < DPTH; ++k) {
            w1[k] = p1[k * CC]; w3[k] = p3[k * CC]; wB[k] = pB[k * CC];
        }

        // virtual pre-t=0 state: first uniform step then yields correct alpha_0
        float a0 = (lane == 0) ? 0.f : NEG;
        float a1 = NEG, a2 = NEG, a3 = NEG, a4 = NEG;

        // shared-lse2 step: lse3(x,y,z) == lse2(x, lse2(y,z)); inner nodes reused
#define STEPK(k) {                                                     \
            float emB = wB[k] * LOG2E;                                 \
            float em1 = w1[k] * LOG2E;                                 \
            float em3 = w3[k] * LOG2E;                                 \
            float pp = shr1_neg(a3);                                   \
            float t_ = lse2(a0, pp);                                   \
            float n0 = emB + t_;                                       \
            float n1 = em1 + lse2(a1, t_);                             \
            float u_ = lse2(a2, a1);                                   \
            float n2 = emB + u_;                                       \
            float n3 = em3 + lse2(a3, u_);                             \
            float n4 = emB + lse2(a4, a3);                             \
            a0 = n0; a1 = n1; a2 = n2; a3 = n3; a4 = n4; }

        // main: t = 0..TT-DPTH-1, prefetching t+DPTH into the freed slot
        for (int tb = 0; tb < TT - DPTH; tb += DPTH) {
            const float* q1 = p1 + (size_t)(tb + DPTH) * CC;
            const float* q3 = p3 + (size_t)(tb + DPTH) * CC;
            const float* qB = pB + (size_t)(tb + DPTH) * CC;
            #pragma unroll
            for (int k = 0; k < DPTH; ++k) {
                STEPK(k);                                  // consume slot k (t=tb+k)
                w1[k] = q1[k * CC];                        // reload slot k (t=tb+k+8)
                w3[k] = q3[k * CC];
                wB[k] = qB[k * CC];
                MWALL();                                   // pin loads to this step
            }
        }
        // epilogue: consume t = TT-DPTH .. TT-1 (no prefetch)
        #pragma unroll
        for (int k = 0; k < DPTH; ++k) STEPK(k);

        // accepting states 255 (lane63 a3) and 256 (lane63 a4)
        if (lane == 63) ll2[b] = lse2(a3, a4);
        return;
    }
    // ---- softmax normalizer: one wave per (b,t) row, grid-strided ----
    int w = (blockIdx.x - BB) * 4 + (threadIdx.x >> 6);
    int lane = threadIdx.x & 63;
    const int stride = LSE_BLOCKS * 4;
    for (int row = w; row < BB * TT; row += stride) {
        float x = in[(size_t)row * CC + lane];
        float m = x;
        #pragma unroll
        for (int d = 32; d >= 1; d >>= 1) m = fmaxf(m, __shfl_xor(m, d, 64));
        float s = fexp2((x - m) * LOG2E);
        #pragma unroll
        for (int d = 32; d >= 1; d >>= 1) s += __shfl_xor(s, d, 64);
        if (lane == 0) lse[row] = m + flog2(s) * LN2f;
    }
}

// per-batch loss_b = sum_t lse_nat[b,t] - ll2[b]*ln2
__global__ __launch_bounds__(256) void bsum_kernel(const float* __restrict__ lse,
                                                   const float* __restrict__ ll2,
                                                   float* __restrict__ lossb) {
    __shared__ float red[256];
    int b = blockIdx.x;
    float s = 0.f;
    for (int i = threadIdx.x; i < TT; i += 256) s += lse[(size_t)b * TT + i];
    red[threadIdx.x] = s;
    __syncthreads();
    #pragma unroll
    for (int w = 128; w >= 1; w >>= 1) {
        if (threadIdx.x < w) red[threadIdx.x] += red[threadIdx.x + w];
        __syncthreads();
    }
    if (threadIdx.x == 0) lossb[b] = red[0] - ll2[b] * LN2f;
}

// mean over batch
__global__ __launch_bounds__(64) void final_kernel(const float* __restrict__ lossb,
                                                   float* __restrict__ out) {
    int lane = threadIdx.x;
    float v = lossb[lane] + lossb[lane + 64];
    #pragma unroll
    for (int d = 32; d >= 1; d >>= 1) v += __shfl_xor(v, d, 64);
    if (lane == 0) out[0] = v / (float)BB;
}

extern "C" void kernel_launch(void* const* d_in, const int* in_sizes, int n_in,
                              void* d_out, int out_size, void* d_ws, size_t ws_size,
                              hipStream_t stream) {
    const float* in = (const float*)d_in[0];
    const int* tg = (const int*)d_in[1];
    float* out = (float*)d_out;
    float* lse = (float*)d_ws;                 // B*T floats
    float* ll2 = lse + (size_t)BB * TT;        // B floats
    float* lossb = ll2 + BB;                   // B floats

    hipLaunchKernelGGL(fused_kernel, dim3(BB + LSE_BLOCKS), dim3(256), 0, stream,
                       in, tg, lse, ll2);
    hipLaunchKernelGGL(bsum_kernel, dim3(BB), dim3(256), 0, stream, lse, ll2, lossb);
    hipLaunchKernelGGL(final_kernel, dim3(1), dim3(64), 0, stream, lossb, out);
}

// Round 8
// 292.291 us; speedup vs baseline: 1.3915x; 1.3915x over previous
//
#include <hip/hip_runtime.h>
#include <stdint.h>

#define BB 128
#define TT 3000
#define CC 64
#define LL 128
// S = 2L+1 = 257
#define NEG (-1e30f)
#define LOG2E 1.4426950408889634f
#define LN2f 0.6931471805599453f
#define F 24                  // frames per LDS ring chunk; 3000 = 125 * 24
#define NCH 125
#define LSE_BLOCKS 512        // extra 8-wave blocks for the softmax-normalizer pass

typedef float f32x2 __attribute__((ext_vector_type(2)));

__device__ __forceinline__ float fexp2(float x) { return __builtin_amdgcn_exp2f(x); }
__device__ __forceinline__ float flog2(float x) { return __builtin_amdgcn_logf(x); }

// base-2 logsumexp of two base-2 log-domain values (6 VALU)
__device__ __forceinline__ float lse2(float x, float y) {
    float m = fmaxf(x, y);
    float e = fexp2(-fabsf(x - y));          // v_exp_f32 with -|.| src modifier
    return m + flog2(1.0f + e);
}
// lane l gets lane l-1's value (lane 0 gets NEG) via DPP wave_shr:1 — VALU speed
__device__ __forceinline__ float shr1_neg(float x) {
    int r = __builtin_amdgcn_update_dpp(__float_as_int(NEG), __float_as_int(x),
                                        0x138 /*wave_shr:1*/, 0xF, 0xF, false);
    return __int_as_float(r);
}
#define SBAR() __builtin_amdgcn_sched_barrier(0)

// Fused kernel, 512 threads/block.
// Blocks 0..BB-1 : CTC scan for batch b. Wave 0 = consumer (recursion, LDS+VALU
//                  only). Waves 1-7 = producers (gather 3 emission channels per
//                  lane from global, pre-scale by LOG2E, stage into a double-
//                  buffered LDS ring). Barrier per 24-frame chunk.
// Blocks BB..    : per-(b,t)-row softmax normalizer (8 waves, grid-strided).
__global__ __launch_bounds__(512) void fused_kernel(const float* __restrict__ in,
                                                    const int* __restrict__ tgt,
                                                    float* __restrict__ lse,
                                                    float* __restrict__ ll2) {
    __shared__ f32x2 ring[2][F][64];   // (em1,em3) per lane per frame
    __shared__ float ringB[2][F];      // blank-channel em per frame
    if (blockIdx.x < BB) {
        const int b = blockIdx.x;
        const int wave = threadIdx.x >> 6;
        const int lane = threadIdx.x & 63;
        const float* fb = in + (size_t)b * TT * CC;
        const int t0 = tgt[b * LL + 2 * lane];      // channel for odd state 4l+1
        const int t1 = tgt[b * LL + 2 * lane + 1];  // channel for odd state 4l+3

        // ---- produce one chunk cc into buffer nb (waves 1..7) ----
#define PRODUCE(cc, nb) {                                                        \
            const int tb_ = (cc) * F;                                            \
            const int p_ = wave - 1;                                             \
            float w1_[4], w3_[4], wb_[4];                                        \
            _Pragma("unroll")                                                    \
            for (int k = 0; k < 4; ++k) {                                        \
                int f_ = p_ + k * 7;                                             \
                if (f_ < F) {                                                    \
                    const float* fr_ = fb + (size_t)(tb_ + f_) * CC;             \
                    w1_[k] = fr_[t0]; w3_[k] = fr_[t1]; wb_[k] = fr_[63];        \
                }                                                                \
            }                                                                    \
            _Pragma("unroll")                                                    \
            for (int k = 0; k < 4; ++k) {                                        \
                int f_ = p_ + k * 7;                                             \
                if (f_ < F) {                                                    \
                    f32x2 v_; v_.x = w1_[k] * LOG2E; v_.y = w3_[k] * LOG2E;      \
                    ring[nb][f_][lane] = v_;                                     \
                    if (lane == 0) ringB[nb][f_] = wb_[k] * LOG2E;               \
                }                                                                \
            }                                                                    \
        }

        if (wave > 0) PRODUCE(0, 0);
        __syncthreads();

        if (wave == 0) {
            // ---------------- consumer ----------------
            __builtin_amdgcn_s_setprio(1);
            const uint32_t ring_base =
                (uint32_t)(uintptr_t)&ring[0][0][0] + (uint32_t)lane * 8u;
            const uint32_t rb_base = (uint32_t)(uintptr_t)&ringB[0][0];

            // virtual pre-t=0 state: first uniform step yields correct alpha_0
            float a0 = (lane == 0) ? 0.f : NEG;
            float a1 = NEG, a2 = NEG, a3 = NEG, a4 = NEG;

            for (int c = 0; c < NCH; ++c) {
                const uint32_t ra = ring_base + (uint32_t)(c & 1) * (F * 64 * 8);
                const uint32_t rb = rb_base + (uint32_t)(c & 1) * (F * 4);
                f32x2 e0, e1, e2; float b0, b1, b2;
                // prologue: issue reads for steps 0 and 1 of this chunk
                asm volatile("ds_read_b64 %0, %1 offset:0"   : "=v"(e0) : "v"(ra));
                asm volatile("ds_read_b32 %0, %1 offset:0"   : "=v"(b0) : "v"(rb));
                asm volatile("ds_read_b64 %0, %1 offset:512" : "=v"(e1) : "v"(ra));
                asm volatile("ds_read_b32 %0, %1 offset:4"   : "=v"(b1) : "v"(rb));
                #pragma unroll
                for (int j = 0; j < F; ++j) {
                    if (j + 2 < F) {   // issue reads for step j+2 (2 ahead)
                        asm volatile("ds_read_b64 %0, %1 offset:%2"
                                     : "=v"(e2) : "v"(ra), "n"((j + 2) * 512));
                        asm volatile("ds_read_b32 %0, %1 offset:%2"
                                     : "=v"(b2) : "v"(rb), "n"((j + 2) * 4));
                        asm volatile("s_waitcnt lgkmcnt(4)" ::: "memory");
                    } else if (j + 2 == F) {
                        asm volatile("s_waitcnt lgkmcnt(2)" ::: "memory");
                    } else {
                        asm volatile("s_waitcnt lgkmcnt(0)" ::: "memory");
                    }
                    SBAR();   // rule #18: keep VALU below the counted wait
                    // shared-lse2 step: lse3(x,y,z) == lse2(x, lse2(y,z))
                    float pp = shr1_neg(a3);
                    float t_ = lse2(a0, pp);
                    float n0 = b0 + t_;
                    float n1 = e0.x + lse2(a1, t_);
                    float u_ = lse2(a2, a1);
                    float n2 = b0 + u_;
                    float n3 = e0.y + lse2(a3, u_);
                    float n4 = b0 + lse2(a4, a3);
                    a0 = n0; a1 = n1; a2 = n2; a3 = n3; a4 = n4;
                    e0 = e1; b0 = b1; e1 = e2; b1 = b2;   // rotate window
                }
                __syncthreads();
            }
            // accepting states 255 (lane63 a3) and 256 (lane63 a4)
            if (lane == 63) ll2[b] = lse2(a3, a4);
        } else {
            // ---------------- producers ----------------
            for (int c = 0; c < NCH; ++c) {
                if (c + 1 < NCH) PRODUCE(c + 1, (c + 1) & 1);
                __syncthreads();
            }
        }
        return;
    }
    // ---- softmax normalizer: one wave per (b,t) row, grid-strided ----
    int w = (blockIdx.x - BB) * 8 + (threadIdx.x >> 6);
    int lane = threadIdx.x & 63;
    const int stride = LSE_BLOCKS * 8;
    for (int row = w; row < BB * TT; row += stride) {
        float x = in[(size_t)row * CC + lane];
        float m = x;
        #pragma unroll
        for (int d = 32; d >= 1; d >>= 1) m = fmaxf(m, __shfl_xor(m, d, 64));
        float s = fexp2((x - m) * LOG2E);
        #pragma unroll
        for (int d = 32; d >= 1; d >>= 1) s += __shfl_xor(s, d, 64);
        if (lane == 0) lse[row] = m + flog2(s) * LN2f;
    }
}

// per-batch loss_b = sum_t lse_nat[b,t] - ll2[b]*ln2
__global__ __launch_bounds__(256) void bsum_kernel(const float* __restrict__ lse,
                                                   const float* __restrict__ ll2,
                                                   float* __restrict__ lossb) {
    __shared__ float red[256];
    int b = blockIdx.x;
    float s = 0.f;
    for (int i = threadIdx.x; i < TT; i += 256) s += lse[(size_t)b * TT + i];
    red[threadIdx.x] = s;
    __syncthreads();
    #pragma unroll
    for (int w = 128; w >= 1; w >>= 1) {
        if (threadIdx.x < w) red[threadIdx.x] += red[threadIdx.x + w];
        __syncthreads();
    }
    if (threadIdx.x == 0) lossb[b] = red[0] - ll2[b] * LN2f;
}

// mean over batch
__global__ __launch_bounds__(64) void final_kernel(const float* __restrict__ lossb,
                                                   float* __restrict__ out) {
    int lane = threadIdx.x;
    float v = lossb[lane] + lossb[lane + 64];
    #pragma unroll
    for (int d = 32; d >= 1; d >>= 1) v += __shfl_xor(v, d, 64);
    if (lane == 0) out[0] = v / (float)BB;
}

extern "C" void kernel_launch(void* const* d_in, const int* in_sizes, int n_in,
                              void* d_out, int out_size, void* d_ws, size_t ws_size,
                              hipStream_t stream) {
    const float* in = (const float*)d_in[0];
    const int* tg = (const int*)d_in[1];
    float* out = (float*)d_out;
    float* lse = (float*)d_ws;                 // B*T floats
    float* ll2 = lse + (size_t)BB * TT;        // B floats
    float* lossb = ll2 + BB;                   // B floats

    hipLaunchKernelGGL(fused_kernel, dim3(BB + LSE_BLOCKS), dim3(512), 0, stream,
                       in, tg, lse, ll2);
    hipLaunchKernelGGL(bsum_kernel, dim3(BB), dim3(256), 0, stream, lse, ll2, lossb);
    hipLaunchKernelGGL(final_kernel, dim3(1), dim3(64), 0, stream, lossb, out);
}

// Round 9
// 241.243 us; speedup vs baseline: 1.6859x; 1.2116x over previous
//
#include <hip/hip_runtime.h>
#include <stdint.h>

#define BB 128
#define TT 3000
#define CC 64
#define LL 128
// S = 2L+1 = 257
#define NEG (-1e30f)
#define LOG2E 1.4426950408889634f
#define LN2f 0.6931471805599453f
#define F 24                  // frames per ring chunk; 3000 = 125 * 24
#define NCH 125
#define LSE_BLOCKS 512        // extra 8-wave blocks for the softmax-normalizer pass

__device__ __forceinline__ float fexp2(float x) { return __builtin_amdgcn_exp2f(x); }
__device__ __forceinline__ float flog2(float x) { return __builtin_amdgcn_logf(x); }

// base-2 logsumexp of two base-2 log-domain values (2 trans + 4 VALU)
__device__ __forceinline__ float lse2(float x, float y) {
    float m = fmaxf(x, y);
    float e = fexp2(-fabsf(x - y));
    return m + flog2(1.0f + e);
}
// lane l gets lane l-1's value (lane 0 gets NEG) via DPP wave_shr:1
__device__ __forceinline__ float shr1_neg(float x) {
    int r = __builtin_amdgcn_update_dpp(__float_as_int(NEG), __float_as_int(x),
                                        0x138 /*wave_shr:1*/, 0xF, 0xF, false);
    return __int_as_float(r);
}
#define SBAR() __builtin_amdgcn_sched_barrier(0)

// Fused kernel, 512 threads/block.
// Scan blocks: wave0 = consumer A (states 0..127, 2/lane), wave1 = consumer B
// (states 128..256, 2/lane + state 256 on lane63's a4 track), waves 2..7 =
// producers. A passes state-127 alphas to B via an LDS boundary ring; B runs
// one chunk behind A (phase-lagged pipeline). Em ring is triple-buffered
// (A at chunk c, B at c-1, producers filling c+1).
__global__ __launch_bounds__(512) void fused_kernel(const float* __restrict__ in,
                                                    const int* __restrict__ tgt,
                                                    float* __restrict__ lse,
                                                    float* __restrict__ ll2) {
    __shared__ float ringT[3][F][128];   // per frame: [0..63]=A-lane ch, [64..127]=B-lane ch
    __shared__ float ringBl[3][F];       // blank-channel em per frame
    __shared__ float bndr[3][F];         // state-127 alpha per step, slot = chunk%3
    __shared__ float dump[64];           // scratch for non-lane63 boundary writes
    if (blockIdx.x < BB) {
        const int b = blockIdx.x;
        const int wave = threadIdx.x >> 6;
        const int lane = threadIdx.x & 63;
        const float* fb = in + (size_t)b * TT * CC;

        if (wave >= 2) {
            // ---------------- producers (6 waves, 4 frames each) ----------------
            const int p = wave - 2;
            const int t0 = tgt[b * LL + lane];        // A-lane channel
            const int t1 = tgt[b * LL + 64 + lane];   // B-lane channel
            auto produce = [&](int cc) {
                const int slot = cc % 3;
                const float* base = fb + (size_t)cc * F * CC;
                float v0[4], v1[4], vb[4];
                #pragma unroll
                for (int k = 0; k < 4; ++k) {
                    const float* fr = base + (p * 4 + k) * CC;
                    v0[k] = fr[t0]; v1[k] = fr[t1]; vb[k] = fr[63];
                }
                #pragma unroll
                for (int k = 0; k < 4; ++k) {
                    int f = p * 4 + k;
                    ringT[slot][f][lane] = v0[k] * LOG2E;
                    ringT[slot][f][64 + lane] = v1[k] * LOG2E;
                    if (lane == 0) ringBl[slot][f] = vb[k] * LOG2E;
                }
            };
            produce(0);
            __syncthreads();
            for (int ph = 0; ph <= NCH; ++ph) {
                if (ph + 1 < NCH) produce(ph + 1);
                __syncthreads();
            }
        } else if (wave == 0) {
            // ---------------- consumer A: states 0..127 ----------------
            __builtin_amdgcn_s_setprio(1);
            float a0 = (lane == 0) ? 0.f : NEG, a1 = NEG;  // virtual pre-t=0 state
            const uint32_t raT = (uint32_t)(uintptr_t)&ringT[0][0][0] + lane * 4u;
            const uint32_t rbB = (uint32_t)(uintptr_t)&ringBl[0][0];
            const uint32_t bnd0 = (uint32_t)(uintptr_t)&bndr[0][0];
            const uint32_t dmp = (uint32_t)(uintptr_t)&dump[0] + lane * 4u;
            const bool is63 = (lane == 63);
            __syncthreads();
            for (int ph = 0; ph <= NCH; ++ph) {
                if (ph < NCH) {
                    const int slot = ph % 3;
                    const uint32_t ra = raT + slot * (F * 128 * 4);
                    const uint32_t rb = rbB + slot * (F * 4);
                    uint32_t wa = is63 ? (bnd0 + slot * (F * 4)) : dmp;
                    const uint32_t wi = is63 ? 4u : 0u;
                    float e0, e1, e2, b0, b1, b2;
                    asm volatile("ds_read_b32 %0, %1 offset:0"   : "=v"(e0) : "v"(ra));
                    asm volatile("ds_read_b32 %0, %1 offset:0"   : "=v"(b0) : "v"(rb));
                    asm volatile("ds_read_b32 %0, %1 offset:512" : "=v"(e1) : "v"(ra));
                    asm volatile("ds_read_b32 %0, %1 offset:4"   : "=v"(b1) : "v"(rb));
                    #pragma unroll
                    for (int j = 0; j < F; ++j) {
                        if (j + 2 < F) {
                            asm volatile("ds_read_b32 %0, %1 offset:%2"
                                         : "=v"(e2) : "v"(ra), "n"((j + 2) * 512));
                            asm volatile("ds_read_b32 %0, %1 offset:%2"
                                         : "=v"(b2) : "v"(rb), "n"((j + 2) * 4));
                            // DS queue incl. our ds_write: steady leaves 5
                            if (j == 0) asm volatile("s_waitcnt lgkmcnt(4)" ::: "memory");
                            else        asm volatile("s_waitcnt lgkmcnt(5)" ::: "memory");
                        } else if (j + 2 == F) {
                            asm volatile("s_waitcnt lgkmcnt(3)" ::: "memory");
                        } else {
                            asm volatile("s_waitcnt lgkmcnt(1)" ::: "memory");
                        }
                        SBAR();
                        float pm = shr1_neg(a1);            // state 2l-1 at t-1
                        float t_ = lse2(a0, pm);            // even state 2l
                        float n0 = b0 + t_;
                        float n1 = e0 + lse2(a1, t_);       // odd 2l+1 (skip via t_)
                        a0 = n0; a1 = n1;
                        asm volatile("ds_write_b32 %0, %1" :: "v"(wa), "v"(a1));
                        wa += wi;
                        e0 = e1; b0 = b1; e1 = e2; b1 = b2;
                    }
                }
                __syncthreads();
            }
        } else {
            // ---------------- consumer B: states 128..256 (1 chunk behind A) ----------------
            __builtin_amdgcn_s_setprio(1);
            float a0 = NEG, a1 = NEG, a4 = NEG;
            const uint32_t raT = (uint32_t)(uintptr_t)&ringT[0][0][0] + (64u + lane) * 4u;
            const uint32_t rbB = (uint32_t)(uintptr_t)&ringBl[0][0];
            const uint32_t bnd0 = (uint32_t)(uintptr_t)&bndr[0][0];
            const bool is0 = (lane == 0);
            __syncthreads();
            for (int ph = 0; ph <= NCH; ++ph) {
                if (ph >= 1) {
                    const int c = ph - 1;
                    const int slot = c % 3;
                    const uint32_t ra = raT + slot * (F * 128 * 4);
                    const uint32_t rb = rbB + slot * (F * 4);
                    const uint32_t br = bnd0 + slot * (F * 4);
                    float e0, e1, e2, b0, b1, b2, q0, q1, q2;
                    if (c == 0) {
                        q0 = NEG;   // alpha_127(-1)
                        asm volatile("ds_read_b32 %0, %1 offset:0"   : "=v"(e0) : "v"(ra));
                        asm volatile("ds_read_b32 %0, %1 offset:0"   : "=v"(b0) : "v"(rb));
                        asm volatile("ds_read_b32 %0, %1 offset:0"   : "=v"(q1) : "v"(br));
                        asm volatile("ds_read_b32 %0, %1 offset:512" : "=v"(e1) : "v"(ra));
                        asm volatile("ds_read_b32 %0, %1 offset:4"   : "=v"(b1) : "v"(rb));
                    } else {
                        const uint32_t pv = bnd0 + ((c - 1) % 3) * (F * 4);
                        asm volatile("ds_read_b32 %0, %1 offset:%2"
                                     : "=v"(q0) : "v"(pv), "n"((F - 1) * 4));
                        asm volatile("ds_read_b32 %0, %1 offset:0"   : "=v"(e0) : "v"(ra));
                        asm volatile("ds_read_b32 %0, %1 offset:0"   : "=v"(b0) : "v"(rb));
                        asm volatile("ds_read_b32 %0, %1 offset:0"   : "=v"(q1) : "v"(br));
                        asm volatile("ds_read_b32 %0, %1 offset:512" : "=v"(e1) : "v"(ra));
                        asm volatile("ds_read_b32 %0, %1 offset:4"   : "=v"(b1) : "v"(rb));
                    }
                    #pragma unroll
                    for (int j = 0; j < F; ++j) {
                        if (j + 2 < F) {
                            asm volatile("ds_read_b32 %0, %1 offset:%2"
                                         : "=v"(e2) : "v"(ra), "n"((j + 2) * 512));
                            asm volatile("ds_read_b32 %0, %1 offset:%2"
                                         : "=v"(b2) : "v"(rb), "n"((j + 2) * 4));
                            asm volatile("ds_read_b32 %0, %1 offset:%2"
                                         : "=v"(q2) : "v"(br), "n"((j + 1) * 4));
                            asm volatile("s_waitcnt lgkmcnt(6)" ::: "memory");
                        } else if (j + 2 == F) {
                            asm volatile("s_waitcnt lgkmcnt(3)" ::: "memory");
                        } else {
                            asm volatile("s_waitcnt lgkmcnt(0)" ::: "memory");
                        }
                        SBAR();
                        float pm = shr1_neg(a1);            // state 128+2l-1 at t-1
                        pm = is0 ? q0 : pm;                 // lane0: state 127 from A
                        float t_ = lse2(a0, pm);            // even state 128+2l
                        float n0 = b0 + t_;
                        float n1 = e0 + lse2(a1, t_);       // odd 128+2l+1
                        float n4 = b0 + lse2(a4, a1);       // state 256 (lane63 track)
                        a0 = n0; a1 = n1; a4 = n4;
                        e0 = e1; b0 = b1; q0 = q1; e1 = e2; b1 = b2; q1 = q2;
                    }
                }
                __syncthreads();
            }
            // accepting states 255 (lane63 a1) and 256 (lane63 a4)
            if (lane == 63) ll2[b] = lse2(a1, a4);
        }
        return;
    }
    // ---- softmax normalizer: one wave per (b,t) row, grid-strided ----
    int w = (blockIdx.x - BB) * 8 + (threadIdx.x >> 6);
    int lane = threadIdx.x & 63;
    const int stride = LSE_BLOCKS * 8;
    for (int row = w; row < BB * TT; row += stride) {
        float x = in[(size_t)row * CC + lane];
        float m = x;
        #pragma unroll
        for (int d = 32; d >= 1; d >>= 1) m = fmaxf(m, __shfl_xor(m, d, 64));
        float s = fexp2((x - m) * LOG2E);
        #pragma unroll
        for (int d = 32; d >= 1; d >>= 1) s += __shfl_xor(s, d, 64);
        if (lane == 0) lse[row] = m + flog2(s) * LN2f;
    }
}

// per-batch loss_b = sum_t lse_nat[b,t] - ll2[b]*ln2
__global__ __launch_bounds__(256) void bsum_kernel(const float* __restrict__ lse,
                                                   const float* __restrict__ ll2,
                                                   float* __restrict__ lossb) {
    __shared__ float red[256];
    int b = blockIdx.x;
    float s = 0.f;
    for (int i = threadIdx.x; i < TT; i += 256) s += lse[(size_t)b * TT + i];
    red[threadIdx.x] = s;
    __syncthreads();
    #pragma unroll
    for (int w = 128; w >= 1; w >>= 1) {
        if (threadIdx.x < w) red[threadIdx.x] += red[threadIdx.x + w];
        __syncthreads();
    }
    if (threadIdx.x == 0) lossb[b] = red[0] - ll2[b] * LN2f;
}

// mean over batch
__global__ __launch_bounds__(64) void final_kernel(const float* __restrict__ lossb,
                                                   float* __restrict__ out) {
    int lane = threadIdx.x;
    float v = lossb[lane] + lossb[lane + 64];
    #pragma unroll
    for (int d = 32; d >= 1; d >>= 1) v += __shfl_xor(v, d, 64);
    if (lane == 0) out[0] = v / (float)BB;
}

extern "C" void kernel_launch(void* const* d_in, const int* in_sizes, int n_in,
                              void* d_out, int out_size, void* d_ws, size_t ws_size,
                              hipStream_t stream) {
    const float* in = (const float*)d_in[0];
    const int* tg = (const int*)d_in[1];
    float* out = (float*)d_out;
    float* lse = (float*)d_ws;                 // B*T floats
    float* ll2 = lse + (size_t)BB * TT;        // B floats
    float* lossb = ll2 + BB;                   // B floats

    hipLaunchKernelGGL(fused_kernel, dim3(BB + LSE_BLOCKS), dim3(512), 0, stream,
                       in, tg, lse, ll2);
    hipLaunchKernelGGL(bsum_kernel, dim3(BB), dim3(256), 0, stream, lse, ll2, lossb);
    hipLaunchKernelGGL(final_kernel, dim3(1), dim3(64), 0, stream, lossb, out);
}